// Round 5
// baseline (425.800 us; speedup 1.0000x reference)
//
#include <hip/hip_runtime.h>
#include <hip/hip_bf16.h>
#include <math.h>

#define NPTS 262144
#define TM   64      // points per block
#define NTHR 512     // 8 waves (R15: 8-wave v2)
// LDS strides chosen for the TRANSPOSED frag access (lane = g*16+p reads
// row p at k-offset g*8): bank-quad = p*(AS/8) + g (mod 32). AS/8 must be
// ===2 (mod 32) so 2p+g covers each bank exactly twice (2-way = free, m136).
// R12 LESSON (32x32x16, 310->342us REGRESSION): 4 independent acc chains
// per K-step can't hide MFMA+LDS latency; >=8 chains needed. Keep 16x16x32.
// R13 LESSON (bb double-buffer): neutral + reg spill. Stall is COVERAGE
// (3 waves/SIMD at 144 regs/wave), not per-step latency.
// R14 LESSON (8 waves, NFW=2, 1-deep wreg, launch_bounds(512,6)=85-reg cap):
// FAILED absmax 0.023/468. Bug not identified by inspection; suspects were
// the new 1-deep wreg, the 85-reg forced-spill cap, or reordering around
// the guarded heads. R15 v2 bisects: EXACT R2 2-deep wreg, 128-reg cap
// (512,4), defensive barriers after dirs-embed and sigma. If v2 fails too,
// the 8-wave decomposition is structurally broken -> revert to R2 for good.
#define AS   272     // 34*16B rows (34 === 2 mod 32)
#define PS   80      // 10*16B rows (10 === 2 mod 32)

#define WS_SHORTS 593920   // prepacked weight image (bf16 elems)

typedef short  short8  __attribute__((ext_vector_type(8)));
typedef float  floatx4 __attribute__((ext_vector_type(4)));

__device__ __forceinline__ unsigned short f2b(float f) {  // RNE
  union { float f; unsigned int i; } v; v.f = f;
  return (unsigned short)((v.i + 0x7fffu + ((v.i >> 16) & 1u)) >> 16);
}
__device__ __forceinline__ float b2f(unsigned short u) {
  union { unsigned int i; float f; } v; v.i = ((unsigned int)u) << 16; return v.f;
}

// ---------------- weight prepack (identical image since R5) ----------------
// u = nf*512 + lane*8 + j  ->  W[n = nf*16 + (lane&15)][k = c*32 + (lane>>4)*8 + j]
struct PrepArgs {
  const float* src[10];
  unsigned short* ws;
  long long dst[10];
  int steps[10];
  int ksrc[10];
  int mode[10];   // 0: direct, 1: zero-pad >=ksrc, 2: L5 remap [base(256)|p(63)|pad]
  int nf16[10];
};

__global__ __launch_bounds__(256) void prep_weights(PrepArgs P) {
  int jl = blockIdx.x, c = blockIdx.y;
  if (c >= P.steps[jl]) return;
  const int NF = P.nf16[jl], tot = NF * 512;
  const float* src = P.src[jl];
  const int Ks = P.ksrc[jl], mode = P.mode[jl];
  unsigned short* dst = P.ws + P.dst[jl] + (long long)c * tot;
  for (int u = threadIdx.x; u < tot; u += 256) {
    int j = u & 7, lane = (u >> 3) & 63, nf = u >> 9;
    int n  = nf * 16 + (lane & 15);
    int kp = c * 32 + ((lane >> 4) << 3) + j;
    int sc;
    if (mode == 0)      sc = kp;
    else if (mode == 1) sc = (kp < Ks) ? kp : -1;
    else                sc = (kp < 256) ? kp + 63 : (kp < Ks ? kp - 256 : -1);
    dst[u] = (sc >= 0) ? f2b(src[(long long)n * Ks + sc]) : (unsigned short)0;
  }
}

struct NerfArgs {
  const float* pts;
  const float* dirs;
  const unsigned short* ws;
  const float* bias[10];   // bb0..bb7, brm, br0
  const float* Wsig;
  const float* bsig;
  const float* Wr1;
  const float* br1;
  float* out;
};

// One layer: relu(act[64 x K] @ W^T + bias) -> act (in-place safe).
// TRANSPOSE TRICK: D^T = (W-tile) x (act-tile); each lane gets 4 contiguous
// channels for point col=lane&15 -> 8B ds_write_b64 epilogue (packed
// v_cvt_pk_bf16_f32 via __float22bfloat162_rn, RNE = bit-identical to f2b).
// 8 waves, NFW=2: wave owns channels [wave*32, wave*32+32). W-frags stream
// from global (L2-hot prepacked image), 2-deep rotating register prefetch
// (EXACT R2 scheme). act-frags from PADDED LDS: every ds address =
// loop-invariant base + compile-time immediate.
// T5: s_setprio(1) around the MFMA cluster (m191 role-diversity regime).
// REGISTER BUDGET: acc 32 + wreg 24 + b 16 + misc ~25 ~= 97 <= 128 cap at
// launch_bounds(512,4) -> 2 blocks/CU = 16 waves/CU (vs R2's ~10-12), even
// 8 generations of 2 blocks/CU (no tail gen). Spill tripwire: FETCH >> 10MB.
template<int NFTOT, int NFW, int STEPS, int STEPS0, int LD0, int LD1>
__device__ __forceinline__ void gemm_g(
    const unsigned short* wimg,
    const short* seg0, const short* seg1,
    const float* bias, short* dst, int tid)
{
  const int lane = tid & 63, wave = tid >> 6;   // wave 0..7
  const int prow = lane & 15;
  const int r4   = (lane >> 4) * 4;
  const int koff = (lane >> 4) * 8;

  // acc = bias (broadcast across points); bv dead after this block
  floatx4 acc[4][NFW];
  {
    float4 bv[NFW];
#pragma unroll
    for (int i = 0; i < NFW; ++i)
      bv[i] = *(const float4*)(bias + (wave * NFW + i) * 16 + r4);
#pragma unroll
    for (int mf = 0; mf < 4; ++mf)
#pragma unroll
      for (int i = 0; i < NFW; ++i) {
        acc[mf][i][0] = bv[i].x; acc[mf][i][1] = bv[i].y;
        acc[mf][i][2] = bv[i].z; acc[mf][i][3] = bv[i].w;
      }
  }

  const unsigned short* wl = wimg + (size_t)(wave * NFW) * 512 + (size_t)lane * 8;
  const short* b0 = seg0 + (size_t)prow * LD0 + koff;   // loop-invariant bases
  const short* b1 = seg1 + (size_t)prow * LD1 + koff;

  // 2-deep rotating weight prefetch; all indices compile-time under unroll
  short8 wreg[3][NFW];
#pragma unroll
  for (int i = 0; i < NFW; ++i) wreg[0][i] = *(const short8*)(wl + i * 512);
  if (STEPS > 1) {
#pragma unroll
    for (int i = 0; i < NFW; ++i)
      wreg[1][i] = *(const short8*)(wl + (size_t)(NFTOT * 512) + i * 512);
  }

#pragma unroll
  for (int s = 0; s < STEPS; ++s) {
    if (s + 2 < STEPS) {
      const unsigned short* wn = wl + (size_t)(s + 2) * (NFTOT * 512);
#pragma unroll
      for (int i = 0; i < NFW; ++i)
        wreg[(s + 2) % 3][i] = *(const short8*)(wn + i * 512);
    }
    short8 b[4];
#pragma unroll
    for (int mf = 0; mf < 4; ++mf) {
      // act[point = mf*16+prow][kl+koff .. +7]; offset is a compile-time imm
      if (s < STEPS0) b[mf] = *(const short8*)(b0 + mf * 16 * LD0 + s * 32);
      else            b[mf] = *(const short8*)(b1 + mf * 16 * LD1 + (s - STEPS0) * 32);
    }
    __builtin_amdgcn_s_setprio(1);
#pragma unroll
    for (int mf = 0; mf < 4; ++mf)
#pragma unroll
      for (int i = 0; i < NFW; ++i)
        acc[mf][i] = __builtin_amdgcn_mfma_f32_16x16x32_bf16(wreg[s % 3][i], b[mf], acc[mf][i], 0, 0, 0);
    __builtin_amdgcn_s_setprio(0);
  }
  __syncthreads();   // all waves' K-loop reads complete before in-place writes
  // D^T C/D layout: channel n = (wave*NFW+i)*16 + r4 + r, point = mf*16 + prow
  short* dstb = dst + (size_t)prow * AS + wave * NFW * 16 + r4;  // loop-invariant base
#pragma unroll
  for (int i = 0; i < NFW; ++i) {
#pragma unroll
    for (int mf = 0; mf < 4; ++mf) {
      float v0 = fmaxf(acc[mf][i][0], 0.f);
      float v1 = fmaxf(acc[mf][i][1], 0.f);
      float v2 = fmaxf(acc[mf][i][2], 0.f);
      float v3 = fmaxf(acc[mf][i][3], 0.f);
      __hip_bfloat162 h01 = __float22bfloat162_rn(make_float2(v0, v1));
      __hip_bfloat162 h23 = __float22bfloat162_rn(make_float2(v2, v3));
      int2 pk;
      pk.x = *(const int*)&h01;
      pk.y = *(const int*)&h23;
      *(int2*)(dstb + mf * 16 * AS + i * 16) = pk;   // compile-time imm offset
    }
  }
  __syncthreads();
}

__global__ __launch_bounds__(NTHR, 4)   // 128-reg cap, 2 blocks/CU: see note
void nerf_fused(NerfArgs A) {
  __shared__ alignas(16) short act[TM * AS];   // 34816 B
  __shared__ alignas(16) short pbuf[TM * PS];  // 10240 B  -> 45056 B total
  const int tid = threadIdx.x;
  const int lane = tid & 63, wave = tid >> 6;
  const size_t gbase = (size_t)blockIdx.x * TM;

  // pts embed, parallel over (row, dim): 192 threads; col 63 zero by 64 more.
  // Trig: libm seed every 4 octaves + doubling (sin2a=2sc, cos2a=1-2s^2);
  // <=3 doublings per seed -> err ~5e-7, invisible vs bf16 storage.
  if (tid < 192) {
    int row = tid & 63, dim = tid >> 6;
    float x = A.pts[(gbase + row) * 3 + dim];
    short* pr = pbuf + row * PS;
    pr[dim] = (short)f2b(x);
    float s = 0.f, c = 0.f, fr = 1.f;
#pragma unroll
    for (int q = 0; q < 10; ++q) {
      if ((q & 3) == 0) { s = sinf(x * fr); c = cosf(x * fr); }
      pr[3 + q * 6 + dim]     = (short)f2b(s);
      pr[3 + q * 6 + 3 + dim] = (short)f2b(c);
      float ns = 2.f * s * c;
      float nc = 1.f - 2.f * s * s;
      s = ns; c = nc;
      fr *= 2.f;
    }
  } else if (tid < 256) {
    pbuf[(tid - 192) * PS + 63] = 0;
  }
  __syncthreads();

  const short* actp = act;
  short*       actw = act;
  const short* pbp  = pbuf;
  const unsigned short* ws = A.ws;

  gemm_g<16, 2,  2, 2, PS, AS>(ws + 0,      pbp,  actp, A.bias[0], actw, tid);
  gemm_g<16, 2,  8, 8, AS, AS>(ws + 16384,  actp, actp, A.bias[1], actw, tid);
  gemm_g<16, 2,  8, 8, AS, AS>(ws + 81920,  actp, actp, A.bias[2], actw, tid);
  gemm_g<16, 2,  8, 8, AS, AS>(ws + 147456, actp, actp, A.bias[3], actw, tid);
  gemm_g<16, 2,  8, 8, AS, AS>(ws + 212992, actp, actp, A.bias[4], actw, tid);
  gemm_g<16, 2, 10, 8, AS, PS>(ws + 278528, actp, pbp,  A.bias[5], actw, tid);

  // p dead: dirs embed into pbuf (cols 0..26; 27..31 zero) + d output.
  // d written as 27 CONTIGUOUS f32 per thread (measured clean WRITE=31MB).
  // Trig: exact seed + 3 doublings (err <1e-6 on the exactly-compared d).
  if (tid >= 64 && tid < 128) {
    int row = tid - 64;
    size_t g = gbase + row;
    float x0 = A.dirs[g * 3 + 0];
    float x1 = A.dirs[g * 3 + 1];
    float x2 = A.dirs[g * 3 + 2];
    float vals[27];
    vals[0] = x0; vals[1] = x1; vals[2] = x2;
    float sx = sinf(x0), cx = cosf(x0);
    float sy = sinf(x1), cy = cosf(x1);
    float sz = sinf(x2), cz = cosf(x2);
#pragma unroll
    for (int q = 0; q < 4; ++q) {
      vals[3 + q * 6 + 0] = sx;
      vals[3 + q * 6 + 1] = sy;
      vals[3 + q * 6 + 2] = sz;
      vals[3 + q * 6 + 3] = cx;
      vals[3 + q * 6 + 4] = cy;
      vals[3 + q * 6 + 5] = cz;
      float nsx = 2.f * sx * cx, ncx = 1.f - 2.f * sx * sx;
      float nsy = 2.f * sy * cy, ncy = 1.f - 2.f * sy * sy;
      float nsz = 2.f * sz * cz, ncz = 1.f - 2.f * sz * sz;
      sx = nsx; cx = ncx; sy = nsy; cy = ncy; sz = nsz; cz = ncz;
    }
    short* dr = pbuf + row * PS;
    float* og = A.out + (size_t)4 * NPTS + g * 27;
    for (int j = 0; j < 27; ++j) {
      dr[j] = (short)f2b(vals[j]);
      og[j] = vals[j];
    }
    for (int j = 27; j < 32; ++j) dr[j] = 0;
  }
  __syncthreads();   // R15: explicit — pbuf writes visible before any later use

  gemm_g<16, 2,  8, 8, AS, AS>(ws + 360448, actp, actp, A.bias[6], actw, tid);
  gemm_g<16, 2,  8, 8, AS, AS>(ws + 425984, actp, actp, A.bias[7], actw, tid);

  // sigma head (SIGMA_MUL=0 -> passthrough), waves 0..3:
  // point = wave*16+(lane&15), k-quarter = lane>>4
  if (wave < 4) {
    int p = wave * 16 + (lane & 15);
    int q = lane >> 4;
    float s = 0.f;
    for (int c8 = 0; c8 < 8; ++c8) {
      int k0 = q * 64 + c8 * 8;
      short8 v = *(const short8*)(act + p * AS + k0);
      const float4 w0 = *(const float4*)(A.Wsig + k0);
      const float4 w1 = *(const float4*)(A.Wsig + k0 + 4);
      s += b2f((unsigned short)v[0]) * w0.x + b2f((unsigned short)v[1]) * w0.y
         + b2f((unsigned short)v[2]) * w0.z + b2f((unsigned short)v[3]) * w0.w
         + b2f((unsigned short)v[4]) * w1.x + b2f((unsigned short)v[5]) * w1.y
         + b2f((unsigned short)v[6]) * w1.z + b2f((unsigned short)v[7]) * w1.w;
    }
    s += __shfl_xor(s, 16);
    s += __shfl_xor(s, 32);
    if (q == 0) A.out[(size_t)3 * NPTS + gbase + p] = s + A.bsig[0];
  }
  __syncthreads();   // R15: explicit — sigma's act reads complete before rm writes

  gemm_g<16, 2,  8, 8, AS, AS>(ws + 491520, actp, actp, A.bias[8], actw, tid);
  gemm_g< 8, 1,  9, 8, AS, PS>(ws + 557056, actp, pbp,  A.bias[9], actw, tid);

  // rgb head: sigmoid(fea[128] @ Wr1^T + br1), waves 0..3:
  // point = wave*16+(lane&15), k-quarter = lane>>4
  if (wave < 4) {
    int p = wave * 16 + (lane & 15);
    int q = lane >> 4;
    float s0 = 0.f, s1 = 0.f, s2 = 0.f;
    for (int c8 = 0; c8 < 4; ++c8) {
      int k0 = q * 32 + c8 * 8;
      short8 v = *(const short8*)(act + p * AS + k0);
#pragma unroll
      for (int j = 0; j < 8; ++j) {
        float fv = b2f((unsigned short)v[j]);
        s0 += fv * A.Wr1[k0 + j];
        s1 += fv * A.Wr1[128 + k0 + j];
        s2 += fv * A.Wr1[256 + k0 + j];
      }
    }
    s0 += __shfl_xor(s0, 16); s0 += __shfl_xor(s0, 32);
    s1 += __shfl_xor(s1, 16); s1 += __shfl_xor(s1, 32);
    s2 += __shfl_xor(s2, 16); s2 += __shfl_xor(s2, 32);
    if (q == 0) {
      size_t g = gbase + p;
      A.out[g * 3 + 0] = 1.f / (1.f + expf(-(s0 + A.br1[0])));
      A.out[g * 3 + 1] = 1.f / (1.f + expf(-(s1 + A.br1[1])));
      A.out[g * 3 + 2] = 1.f / (1.f + expf(-(s2 + A.br1[2])));
    }
  }
}

extern "C" void kernel_launch(void* const* d_in, const int* in_sizes, int n_in,
                              void* d_out, int out_size, void* d_ws, size_t ws_size,
                              hipStream_t stream) {
  // input order: pts, dirs, (Wb_i, bb_i)*8, Wsig, bsig, Wrm, brm, Wr0, br0, Wr1, br1
  PrepArgs pp;
  const int       widx[10]  = {2, 4, 6, 8, 10, 12, 14, 16, 20, 22};
  const long long doffs[10] = {0, 16384, 81920, 147456, 212992, 278528,
                               360448, 425984, 491520, 557056};
  const int stv[10] = {2, 8, 8, 8, 8, 10, 8, 8, 8, 9};
  const int ksv[10] = {63, 256, 256, 256, 256, 319, 256, 256, 256, 283};
  const int mdv[10] = {1, 0, 0, 0, 0, 2, 0, 0, 0, 1};
  const int nfv[10] = {16, 16, 16, 16, 16, 16, 16, 16, 16, 8};
  pp.ws = (unsigned short*)d_ws;   // needs WS_SHORTS*2 = 1.19 MB (verified fits)
  for (int j = 0; j < 10; ++j) {
    pp.src[j] = (const float*)d_in[widx[j]];
    pp.dst[j] = doffs[j]; pp.steps[j] = stv[j]; pp.ksrc[j] = ksv[j];
    pp.mode[j] = mdv[j]; pp.nf16[j] = nfv[j];
  }
  prep_weights<<<dim3(10, 10), dim3(256), 0, stream>>>(pp);

  NerfArgs na;
  na.pts  = (const float*)d_in[0];
  na.dirs = (const float*)d_in[1];
  na.ws   = (const unsigned short*)d_ws;
  for (int i = 0; i < 8; ++i) na.bias[i] = (const float*)d_in[3 + 2 * i];
  na.bias[8] = (const float*)d_in[21];  // brm
  na.bias[9] = (const float*)d_in[23];  // br0
  na.Wsig = (const float*)d_in[18];
  na.bsig = (const float*)d_in[19];
  na.Wr1  = (const float*)d_in[24];
  na.br1  = (const float*)d_in[25];
  na.out  = (float*)d_out;
  nerf_fused<<<dim3(NPTS / TM), dim3(NTHR), 0, stream>>>(na);
}

// Round 7
// 390.119 us; speedup vs baseline: 1.0915x; 1.0915x over previous
//
#include <hip/hip_runtime.h>
#include <hip/hip_bf16.h>
#include <math.h>

#define NPTS 262144
#define TM   64      // points per block
#define NTHR 256     // 4 waves
// LDS strides for the TRANSPOSED frag access (lane = g*16+p reads row p at
// k-offset g*8): bank-quad = p*(AS/8) + g (mod 32). AS/8 === 2 (mod 32) so
// 2p+g covers each bank exactly twice (2-way = free, m136).
// R12: 32x32x16 starves dependency chains (4/step) -> keep 16x16x32.
// R13: bb act-dbuf = neutral + spill; per-step LDS latency already covered.
// R15: 8 waves x NFW=2 LOSES (MFMA:LDS ratio per wave halves -> LDS-bound).
// R14/R16 FORCED-SPILL CORRECTNESS BUG (absmax 0.02x/468 twice): configs
// whose reg usage EXCEEDS a forced __launch_bounds__ cap miscompute;
// no-slack caps also coincided with the wreg[2]&1 scheme. RULE: keep the
// wreg[3]%3 scheme AND always leave reg slack under the cap. This kills
// 4 blocks/CU (proven body needs ~160 regs; 128-cap can never fit).
// R17: cross-layer W+bias prefetch into dead wreg slots 0/1 after the last
// MFMA cluster, before the pre-epilogue barrier: hides the ~200cy L2
// latency of each layer's first W/bias fetch under barrier+epilogue+init.
// Slot-death check: last two steps read slots {0,1}/{2,0}/{1,2} for
// STEPS=8/10/9; post-loop writes to 0/1 are WAR-safe (in-order issue).
#define AS   272     // 34*16B rows (34 === 2 mod 32)
#define PS   80      // 10*16B rows (10 === 2 mod 32)

#define WS_SHORTS 593920   // prepacked weight image (bf16 elems)

typedef short  short8  __attribute__((ext_vector_type(8)));
typedef float  floatx4 __attribute__((ext_vector_type(4)));

__device__ __forceinline__ unsigned short f2b(float f) {  // RNE
  union { float f; unsigned int i; } v; v.f = f;
  return (unsigned short)((v.i + 0x7fffu + ((v.i >> 16) & 1u)) >> 16);
}
__device__ __forceinline__ float b2f(unsigned short u) {
  union { unsigned int i; float f; } v; v.i = ((unsigned int)u) << 16; return v.f;
}

// ---------------- weight prepack (identical image since R5) ----------------
// u = nf*512 + lane*8 + j  ->  W[n = nf*16 + (lane&15)][k = c*32 + (lane>>4)*8 + j]
struct PrepArgs {
  const float* src[10];
  unsigned short* ws;
  long long dst[10];
  int steps[10];
  int ksrc[10];
  int mode[10];   // 0: direct, 1: zero-pad >=ksrc, 2: L5 remap [base(256)|p(63)|pad]
  int nf16[10];
};

__global__ __launch_bounds__(256) void prep_weights(PrepArgs P) {
  int jl = blockIdx.x, c = blockIdx.y;
  if (c >= P.steps[jl]) return;
  const int NF = P.nf16[jl], tot = NF * 512;
  const float* src = P.src[jl];
  const int Ks = P.ksrc[jl], mode = P.mode[jl];
  unsigned short* dst = P.ws + P.dst[jl] + (long long)c * tot;
  for (int u = threadIdx.x; u < tot; u += 256) {
    int j = u & 7, lane = (u >> 3) & 63, nf = u >> 9;
    int n  = nf * 16 + (lane & 15);
    int kp = c * 32 + ((lane >> 4) << 3) + j;
    int sc;
    if (mode == 0)      sc = kp;
    else if (mode == 1) sc = (kp < Ks) ? kp : -1;
    else                sc = (kp < 256) ? kp + 63 : (kp < Ks ? kp - 256 : -1);
    dst[u] = (sc >= 0) ? f2b(src[(long long)n * Ks + sc]) : (unsigned short)0;
  }
}

struct NerfArgs {
  const float* pts;
  const float* dirs;
  const unsigned short* ws;
  const float* bias[10];   // bb0..bb7, brm, br0
  const float* Wsig;
  const float* bsig;
  const float* Wr1;
  const float* br1;
  float* out;
};

// One layer: relu(act[64 x K] @ W^T + bias) -> act (in-place safe).
// TRANSPOSE TRICK: D^T = (W-tile) x (act-tile); each lane gets 4 contiguous
// channels for point col=lane&15 -> 8B ds_write_b64 epilogue (packed
// v_cvt_pk_bf16_f32 via __float22bfloat162_rn, RNE = bit-identical to f2b).
// W-frags stream from global (L2-hot prepacked image), 2-deep rotating
// register prefetch (%3 scheme — R14/R16 rule). acc starts at BIAS, loaded
// from the bv[] threaded through calls (prefetched by the previous layer).
// act-frags from PADDED LDS: every ds address = loop-invariant base +
// compile-time immediate. T5: s_setprio(1) around the MFMA cluster.
// NFT_N/NFW_N: next layer's geometry for the cross-layer prefetch
// (NFW_N=0 -> no prefetch, last gemm).
template<int NFTOT, int NFW, int STEPS, int STEPS0, int LD0, int LD1,
         int NFT_N, int NFW_N>
__device__ __forceinline__ void gemm_g(
    const unsigned short* wimg,
    const short* seg0, const short* seg1,
    short* dst, int tid,
    short8 wreg[3][4], float4 bv[4],
    const unsigned short* wnext, const float* bnext)
{
  const int lane = tid & 63, wave = tid >> 6;
  const int prow = lane & 15;
  const int r4   = (lane >> 4) * 4;
  const int koff = (lane >> 4) * 8;

  // acc = bias (broadcast across points) — bv preloaded by previous layer
  floatx4 acc[4][NFW];
#pragma unroll
  for (int mf = 0; mf < 4; ++mf)
#pragma unroll
    for (int i = 0; i < NFW; ++i) {
      acc[mf][i][0] = bv[i].x; acc[mf][i][1] = bv[i].y;
      acc[mf][i][2] = bv[i].z; acc[mf][i][3] = bv[i].w;
    }

  const short* b0 = seg0 + (size_t)prow * LD0 + koff;   // loop-invariant bases
  const short* b1 = seg1 + (size_t)prow * LD1 + koff;
  const unsigned short* wl = wimg + (size_t)(wave * NFW) * 512 + (size_t)lane * 8;

#pragma unroll
  for (int s = 0; s < STEPS; ++s) {
    if (s + 2 < STEPS) {
      const unsigned short* wn = wl + (size_t)(s + 2) * (NFTOT * 512);
#pragma unroll
      for (int i = 0; i < NFW; ++i)
        wreg[(s + 2) % 3][i] = *(const short8*)(wn + i * 512);
    }
    short8 b[4];
#pragma unroll
    for (int mf = 0; mf < 4; ++mf) {
      // act[point = mf*16+prow][kl+koff .. +7]; offset is a compile-time imm
      if (s < STEPS0) b[mf] = *(const short8*)(b0 + mf * 16 * LD0 + s * 32);
      else            b[mf] = *(const short8*)(b1 + mf * 16 * LD1 + (s - STEPS0) * 32);
    }
    __builtin_amdgcn_s_setprio(1);
#pragma unroll
    for (int mf = 0; mf < 4; ++mf)
#pragma unroll
      for (int i = 0; i < NFW; ++i)
        acc[mf][i] = __builtin_amdgcn_mfma_f32_16x16x32_bf16(wreg[s % 3][i], b[mf], acc[mf][i], 0, 0, 0);
    __builtin_amdgcn_s_setprio(0);
  }

  // R17: cross-layer prefetch into dead wreg slots 0/1 + bv, issued before
  // the barrier so L2 latency hides under barrier+epilogue+barrier+init.
  if (NFW_N > 0) {
    const unsigned short* wn0 = wnext + (size_t)(wave * NFW_N) * 512 + (size_t)lane * 8;
#pragma unroll
    for (int i = 0; i < NFW_N; ++i)
      wreg[0][i] = *(const short8*)(wn0 + i * 512);
#pragma unroll
    for (int i = 0; i < NFW_N; ++i)
      wreg[1][i] = *(const short8*)(wn0 + (size_t)(NFT_N * 512) + i * 512);
#pragma unroll
    for (int i = 0; i < NFW_N; ++i)
      bv[i] = *(const float4*)(bnext + (wave * NFW_N + i) * 16 + r4);
  }

  __syncthreads();   // all waves' K-loop reads complete before in-place writes
  // D^T C/D layout: channel n = (wave*NFW+i)*16 + r4 + r, point = mf*16 + prow
  short* dstb = dst + (size_t)prow * AS + wave * NFW * 16 + r4;  // loop-invariant base
#pragma unroll
  for (int i = 0; i < NFW; ++i) {
#pragma unroll
    for (int mf = 0; mf < 4; ++mf) {
      float v0 = fmaxf(acc[mf][i][0], 0.f);
      float v1 = fmaxf(acc[mf][i][1], 0.f);
      float v2 = fmaxf(acc[mf][i][2], 0.f);
      float v3 = fmaxf(acc[mf][i][3], 0.f);
      __hip_bfloat162 h01 = __float22bfloat162_rn(make_float2(v0, v1));
      __hip_bfloat162 h23 = __float22bfloat162_rn(make_float2(v2, v3));
      int2 pk;
      pk.x = *(const int*)&h01;
      pk.y = *(const int*)&h23;
      *(int2*)(dstb + mf * 16 * AS + i * 16) = pk;   // compile-time imm offset
    }
  }
  __syncthreads();
}

__global__ __launch_bounds__(NTHR, 3)   // 3 blocks/CU; cap 170 with SLACK (R14/R16 rule)
void nerf_fused(NerfArgs A) {
  __shared__ alignas(16) short act[TM * AS];   // 34816 B
  __shared__ alignas(16) short pbuf[TM * PS];  // 10240 B  -> 45056 B total
  const int tid = threadIdx.x;
  const int lane = tid & 63, wave = tid >> 6;
  const size_t gbase = (size_t)blockIdx.x * TM;

  // R17 prologue: preload L0's W steps 0/1 + bias into the threaded
  // wreg/bv BEFORE the embed, so the loads run under the trig.
  short8 wreg[3][4];
  float4 bv[4];
  {
    const unsigned short* w0 = A.ws + (size_t)(wave * 4) * 512 + (size_t)lane * 8;
    const int r4 = (lane >> 4) * 4;
#pragma unroll
    for (int i = 0; i < 4; ++i) wreg[0][i] = *(const short8*)(w0 + i * 512);
#pragma unroll
    for (int i = 0; i < 4; ++i) wreg[1][i] = *(const short8*)(w0 + 16 * 512 + i * 512);
#pragma unroll
    for (int i = 0; i < 4; ++i) bv[i] = *(const float4*)(A.bias[0] + (wave * 4 + i) * 16 + r4);
  }

  // pts embed, parallel over (row, dim): 192 threads; col 63 zero by the rest.
  // Trig: libm seed every 4 octaves + doubling (sin2a=2sc, cos2a=1-2s^2);
  // <=3 doublings per seed -> err ~5e-7, invisible vs bf16 storage.
  // (R12: absmax unchanged at 0.0039.)
  if (tid < 192) {
    int row = tid & 63, dim = tid >> 6;
    float x = A.pts[(gbase + row) * 3 + dim];
    short* pr = pbuf + row * PS;
    pr[dim] = (short)f2b(x);
    float s = 0.f, c = 0.f, fr = 1.f;
#pragma unroll
    for (int q = 0; q < 10; ++q) {
      if ((q & 3) == 0) { s = sinf(x * fr); c = cosf(x * fr); }
      pr[3 + q * 6 + dim]     = (short)f2b(s);
      pr[3 + q * 6 + 3 + dim] = (short)f2b(c);
      float ns = 2.f * s * c;
      float nc = 1.f - 2.f * s * s;
      s = ns; c = nc;
      fr *= 2.f;
    }
  } else {
    pbuf[(tid - 192) * PS + 63] = 0;
  }
  __syncthreads();

  const short* actp = act;
  short*       actw = act;
  const short* pbp  = pbuf;
  const unsigned short* ws = A.ws;

  gemm_g<16, 4,  2, 2, PS, AS, 16, 4>(ws + 0,      pbp,  actp, actw, tid, wreg, bv, ws + 16384,  A.bias[1]);
  gemm_g<16, 4,  8, 8, AS, AS, 16, 4>(ws + 16384,  actp, actp, actw, tid, wreg, bv, ws + 81920,  A.bias[2]);
  gemm_g<16, 4,  8, 8, AS, AS, 16, 4>(ws + 81920,  actp, actp, actw, tid, wreg, bv, ws + 147456, A.bias[3]);
  gemm_g<16, 4,  8, 8, AS, AS, 16, 4>(ws + 147456, actp, actp, actw, tid, wreg, bv, ws + 212992, A.bias[4]);
  gemm_g<16, 4,  8, 8, AS, AS, 16, 4>(ws + 212992, actp, actp, actw, tid, wreg, bv, ws + 278528, A.bias[5]);
  gemm_g<16, 4, 10, 8, AS, PS, 16, 4>(ws + 278528, actp, pbp,  actw, tid, wreg, bv, ws + 360448, A.bias[6]);

  // p dead: dirs embed into pbuf (cols 0..26; 27..31 zero) + d output.
  // d written as 27 CONTIGUOUS f32 per thread (measured clean WRITE=31MB).
  // Scattered per-dim stores (R6-R8) caused partial-line RMW thrash.
  // Trig: exact seed + 3 doublings (err <1e-6 on the exactly-compared d).
  // L5's prefetch of L6 is in flight across this whole section (bonus).
  if (tid >= 64 && tid < 128) {
    int row = tid - 64;
    size_t g = gbase + row;
    float x0 = A.dirs[g * 3 + 0];
    float x1 = A.dirs[g * 3 + 1];
    float x2 = A.dirs[g * 3 + 2];
    float vals[27];
    vals[0] = x0; vals[1] = x1; vals[2] = x2;
    float sx = sinf(x0), cx = cosf(x0);
    float sy = sinf(x1), cy = cosf(x1);
    float sz = sinf(x2), cz = cosf(x2);
#pragma unroll
    for (int q = 0; q < 4; ++q) {
      vals[3 + q * 6 + 0] = sx;
      vals[3 + q * 6 + 1] = sy;
      vals[3 + q * 6 + 2] = sz;
      vals[3 + q * 6 + 3] = cx;
      vals[3 + q * 6 + 4] = cy;
      vals[3 + q * 6 + 5] = cz;
      float nsx = 2.f * sx * cx, ncx = 1.f - 2.f * sx * sx;
      float nsy = 2.f * sy * cy, ncy = 1.f - 2.f * sy * sy;
      float nsz = 2.f * sz * cz, ncz = 1.f - 2.f * sz * sz;
      sx = nsx; cx = ncx; sy = nsy; cy = ncy; sz = nsz; cz = ncz;
    }
    short* dr = pbuf + row * PS;
    float* og = A.out + (size_t)4 * NPTS + g * 27;
    for (int j = 0; j < 27; ++j) {
      dr[j] = (short)f2b(vals[j]);
      og[j] = vals[j];
    }
    for (int j = 27; j < 32; ++j) dr[j] = 0;
  }
  __syncthreads();   // R15-proven: pbuf writes visible before any later use

  gemm_g<16, 4,  8, 8, AS, AS, 16, 4>(ws + 360448, actp, actp, actw, tid, wreg, bv, ws + 425984, A.bias[7]);
  gemm_g<16, 4,  8, 8, AS, AS, 16, 4>(ws + 425984, actp, actp, actw, tid, wreg, bv, ws + 491520, A.bias[8]);

  // sigma head (SIGMA_MUL=0 -> passthrough): point = wave*16+(lane&15).
  // L7's prefetch of rm is in flight across this head (bonus overlap).
  {
    int p = wave * 16 + (lane & 15);
    int q = lane >> 4;
    float s = 0.f;
    for (int c8 = 0; c8 < 8; ++c8) {
      int k0 = q * 64 + c8 * 8;
      short8 v = *(const short8*)(act + p * AS + k0);
      const float4 w0 = *(const float4*)(A.Wsig + k0);
      const float4 w1 = *(const float4*)(A.Wsig + k0 + 4);
      s += b2f((unsigned short)v[0]) * w0.x + b2f((unsigned short)v[1]) * w0.y
         + b2f((unsigned short)v[2]) * w0.z + b2f((unsigned short)v[3]) * w0.w
         + b2f((unsigned short)v[4]) * w1.x + b2f((unsigned short)v[5]) * w1.y
         + b2f((unsigned short)v[6]) * w1.z + b2f((unsigned short)v[7]) * w1.w;
    }
    s += __shfl_xor(s, 16);
    s += __shfl_xor(s, 32);
    if (q == 0) A.out[(size_t)3 * NPTS + gbase + p] = s + A.bsig[0];
  }
  __syncthreads();   // R15-proven: sigma's act reads complete before rm writes

  gemm_g<16, 4,  8, 8, AS, AS,  8, 2>(ws + 491520, actp, actp, actw, tid, wreg, bv, ws + 557056, A.bias[9]);
  gemm_g< 8, 2,  9, 8, AS, PS,  0, 0>(ws + 557056, actp, pbp,  actw, tid, wreg, bv, (const unsigned short*)0, (const float*)0);

  // rgb head: sigmoid(fea[128] @ Wr1^T + br1): point = wave*16+(lane&15)
  {
    int p = wave * 16 + (lane & 15);
    int q = lane >> 4;
    float s0 = 0.f, s1 = 0.f, s2 = 0.f;
    for (int c8 = 0; c8 < 4; ++c8) {
      int k0 = q * 32 + c8 * 8;
      short8 v = *(const short8*)(act + p * AS + k0);
#pragma unroll
      for (int j = 0; j < 8; ++j) {
        float fv = b2f((unsigned short)v[j]);
        s0 += fv * A.Wr1[k0 + j];
        s1 += fv * A.Wr1[128 + k0 + j];
        s2 += fv * A.Wr1[256 + k0 + j];
      }
    }
    s0 += __shfl_xor(s0, 16); s0 += __shfl_xor(s0, 32);
    s1 += __shfl_xor(s1, 16); s1 += __shfl_xor(s1, 32);
    s2 += __shfl_xor(s2, 16); s2 += __shfl_xor(s2, 32);
    if (q == 0) {
      size_t g = gbase + p;
      A.out[g * 3 + 0] = 1.f / (1.f + expf(-(s0 + A.br1[0])));
      A.out[g * 3 + 1] = 1.f / (1.f + expf(-(s1 + A.br1[1])));
      A.out[g * 3 + 2] = 1.f / (1.f + expf(-(s2 + A.br1[2])));
    }
  }
}

extern "C" void kernel_launch(void* const* d_in, const int* in_sizes, int n_in,
                              void* d_out, int out_size, void* d_ws, size_t ws_size,
                              hipStream_t stream) {
  // input order: pts, dirs, (Wb_i, bb_i)*8, Wsig, bsig, Wrm, brm, Wr0, br0, Wr1, br1
  PrepArgs pp;
  const int       widx[10]  = {2, 4, 6, 8, 10, 12, 14, 16, 20, 22};
  const long long doffs[10] = {0, 16384, 81920, 147456, 212992, 278528,
                               360448, 425984, 491520, 557056};
  const int stv[10] = {2, 8, 8, 8, 8, 10, 8, 8, 8, 9};
  const int ksv[10] = {63, 256, 256, 256, 256, 319, 256, 256, 256, 283};
  const int mdv[10] = {1, 0, 0, 0, 0, 2, 0, 0, 0, 1};
  const int nfv[10] = {16, 16, 16, 16, 16, 16, 16, 16, 16, 8};
  pp.ws = (unsigned short*)d_ws;   // needs WS_SHORTS*2 = 1.19 MB (verified fits)
  for (int j = 0; j < 10; ++j) {
    pp.src[j] = (const float*)d_in[widx[j]];
    pp.dst[j] = doffs[j]; pp.steps[j] = stv[j]; pp.ksrc[j] = ksv[j];
    pp.mode[j] = mdv[j]; pp.nf16[j] = nfv[j];
  }
  prep_weights<<<dim3(10, 10), dim3(256), 0, stream>>>(pp);

  NerfArgs na;
  na.pts  = (const float*)d_in[0];
  na.dirs = (const float*)d_in[1];
  na.ws   = (const unsigned short*)d_ws;
  for (int i = 0; i < 8; ++i) na.bias[i] = (const float*)d_in[3 + 2 * i];
  na.bias[8] = (const float*)d_in[21];  // brm
  na.bias[9] = (const float*)d_in[23];  // br0
  na.Wsig = (const float*)d_in[18];
  na.bsig = (const float*)d_in[19];
  na.Wr1  = (const float*)d_in[24];
  na.br1  = (const float*)d_in[25];
  na.out  = (float*)d_out;
  nerf_fused<<<dim3(NPTS / TM), dim3(NTHR), 0, stream>>>(na);
}